// Round 1
// 7326.154 us; speedup vs baseline: 1.3132x; 1.3132x over previous
//
#include <hip/hip_runtime.h>
#include <math.h>

#define TT 64      // total patches
#define SS 729     // spatial tokens
#define HH 1152    // hidden
#define EE 512     // embed/class dim
#define NEm 9      // emotions
#define GELU_K 0.70710678118654752440f

// ---------------- helpers ----------------
__device__ __forceinline__ float blk_reduce(float v, bool is_max, float* red)
{
    #pragma unroll
    for (int off = 32; off >= 1; off >>= 1) {
        float o = __shfl_xor(v, off, 64);
        v = is_max ? fmaxf(v, o) : (v + o);
    }
    __syncthreads();
    if ((threadIdx.x & 63) == 0) red[threadIdx.x >> 6] = v;
    __syncthreads();
    const int nw = blockDim.x >> 6;
    float r = red[0];
    for (int w = 1; w < nw; ++w) r = is_max ? fmaxf(r, red[w]) : (r + red[w]);
    return r;
}

// ---------------- K1: spatial pooling (first patch of each image) ----------------
// grid (8,9), block 128
__global__ void k_pool(const float* __restrict__ ov, const float* __restrict__ pool_w,
                       const float* __restrict__ pool_b, float* __restrict__ pooled)
{
    const int b = blockIdx.x;
    const int h = blockIdx.y * 128 + threadIdx.x;
    const float* base = ov + (size_t)(b * 8) * SS * HH + h;
    float acc = 0.f;
    for (int s = 0; s < SS; ++s) acc = fmaf(base[(size_t)s * HH], pool_w[s], acc);
    pooled[b * HH + h] = acc + pool_b[0];
}

// ---------------- K2: classifier MLP (per image) ----------------
// grid 8, block 512
__global__ void k_cls(const float* __restrict__ pooled,
                      const float* __restrict__ w1, const float* __restrict__ b1,
                      const float* __restrict__ w2, const float* __restrict__ b2,
                      float* __restrict__ cls)
{
    __shared__ float pr[HH];
    __shared__ float c1[EE];
    const int b = blockIdx.x, tid = threadIdx.x;
    for (int h = tid; h < HH; h += 512) pr[h] = pooled[b * HH + h];
    __syncthreads();
    float acc = b1[tid];
    const float* wr = w1 + (size_t)tid * HH;
    for (int h = 0; h < HH; ++h) acc = fmaf(pr[h], wr[h], acc);
    c1[tid] = 0.5f * acc * (1.0f + erff(acc * GELU_K));
    __syncthreads();
    float acc2 = b2[tid];
    const float* w2r = w2 + (size_t)tid * EE;
    for (int c = 0; c < EE; ++c) acc2 = fmaf(c1[c], w2r[c], acc2);
    cls[b * EE + tid] = acc2;
}

// ---------------- K3: emotion prompts (per level,image,emotion) ----------------
// grid (9,8,4), block 256
__global__ __launch_bounds__(256) void k_prompts(
    const float* __restrict__ emo, const float* __restrict__ cls,
    const float* __restrict__ pw, const float* __restrict__ pb,
    float* __restrict__ prompts)
{
    const int n = blockIdx.x, b = blockIdx.y, i = blockIdx.z, tid = threadIdx.x;
    __shared__ float cat[1024];
    __shared__ float red[4];
    for (int c = tid; c < EE; c += 256) {
        cat[c] = emo[n * EE + c];
        cat[EE + c] = cls[b * EE + c];
    }
    __syncthreads();
    float myv[2]; float ns = 0.f;
    #pragma unroll
    for (int rep = 0; rep < 2; ++rep) {
        int o = tid + rep * 256;
        const float* wr = pw + ((size_t)i * EE + o) * 1024;
        float acc = pb[i * EE + o];
        for (int c = 0; c < 1024; ++c) acc = fmaf(cat[c], wr[c], acc);
        myv[rep] = acc; ns = fmaf(acc, acc, ns);
    }
    float norm2 = blk_reduce(ns, false, red);
    float invn = 1.0f / sqrtf(norm2);
    #pragma unroll
    for (int rep = 0; rep < 2; ++rep) {
        int o = tid + rep * 256;
        prompts[(((size_t)(i * 8 + b)) * NEm + n) * EE + o] = myv[rep] * invn;
    }
}

// ---------------- K4 v2: fused siglip GEMM + l2norm + cosine scores ----------------
// grid (12,64,4) = (s-tile of 64, t, level), block 256 (4 waves).
// Register tile 4s x 8o per thread, b128 LDS reads, double-buffered K-chunks of 32,
// issue-early/write-late staging (one barrier per K-chunk).
// LDS-pipe-bound fix: old version did 8 FMA per 6 scalar ds_read_b32 (LDS ~100% busy,
// 1.03e9 conflict cycles); this does 128 FMA per 12 ds_read_b128, conflict-free.
#define BM4 64
#define BN4 128
__global__ __launch_bounds__(256, 2) void k_sigscores(
    const float* __restrict__ sig, const float* __restrict__ sig_w,
    const float* __restrict__ sig_b, const float* __restrict__ prompts,
    float* __restrict__ scores)
{
    const int i = blockIdx.z, t = blockIdx.y;
    const int s0 = blockIdx.x * BM4;
    const int tid = threadIdx.x;
    const int b = t >> 3;

    __shared__ float Alds[2][BM4][36];       // [buf][s][k], +4 pad -> conflict-free b128
    __shared__ float Wlds[2][32][BN4 + 4];   // [buf][k][o], +4 pad
    __shared__ float Plds[NEm][EE];          // prompts for (i,b)

    {   // prompts resident for the whole kernel
        const float* pbase = prompts + ((size_t)(i * 8 + b)) * NEm * EE;
        for (int idx = tid; idx < NEm * EE; idx += 256)
            ((float*)Plds)[idx] = pbase[idx];
    }

    // compute mapping: 16 o-groups x 16 s-groups
    const int og = tid & 15;                 // o = oc*128 + {og*4+j, 64+og*4+j}
    const int sg = tid >> 4;                 // s = s0 + sg*4 + ss

    // staging mapping (A): 64 s x 4 k-quads, 2 reps -> 32 k
    const int sA = tid & 63;
    const int kqA = tid >> 6;                // 0..3
    const int sClamp = (s0 + sA < SS) ? (s0 + sA) : (SS - 1);   // clamp tail rows (garbage rows never stored)
    const float* aBase = sig + ((size_t)(i * TT + t) * SS + sClamp) * HH + kqA * 4;
    // staging mapping (W): 128 o x 2 k-halves, 4 float4 each -> 32 k
    const int oW = tid & 127;
    const int khW = tid >> 7;                // 0..1

    float norm2[4] = {0.f, 0.f, 0.f, 0.f};
    float dots[4][NEm];
    #pragma unroll
    for (int ss = 0; ss < 4; ++ss)
        #pragma unroll
        for (int n = 0; n < NEm; ++n) dots[ss][n] = 0.f;

    for (int oc = 0; oc < 4; ++oc) {
        const float* wBase = sig_w + ((size_t)i * EE + oc * BN4 + oW) * HH + khW * 16;

        float acc[4][8];
        #pragma unroll
        for (int ss = 0; ss < 4; ++ss)
            #pragma unroll
            for (int j = 0; j < 8; ++j) acc[ss][j] = 0.f;

        float4 aSt[2]; float4 wSt[4];
        // ---- prologue: stage kc = 0 into buf 0 ----
        aSt[0] = *(const float4*)(aBase);
        aSt[1] = *(const float4*)(aBase + 16);
        #pragma unroll
        for (int r = 0; r < 4; ++r) wSt[r] = *(const float4*)(wBase + r * 4);
        *(float4*)&Alds[0][sA][kqA * 4]      = aSt[0];
        *(float4*)&Alds[0][sA][kqA * 4 + 16] = aSt[1];
        #pragma unroll
        for (int r = 0; r < 4; ++r) {
            Wlds[0][khW * 16 + r * 4 + 0][oW] = wSt[r].x;
            Wlds[0][khW * 16 + r * 4 + 1][oW] = wSt[r].y;
            Wlds[0][khW * 16 + r * 4 + 2][oW] = wSt[r].z;
            Wlds[0][khW * 16 + r * 4 + 3][oW] = wSt[r].w;
        }
        __syncthreads();

        int buf = 0;
        for (int kc = 0; kc < 36; ++kc) {
            // issue next chunk's global loads BEFORE compute (latency hides under FMAs)
            if (kc + 1 < 36) {
                const float* ap = aBase + (size_t)(kc + 1) * 32;
                aSt[0] = *(const float4*)(ap);
                aSt[1] = *(const float4*)(ap + 16);
                const float* wp = wBase + (size_t)(kc + 1) * 32;
                #pragma unroll
                for (int r = 0; r < 4; ++r) wSt[r] = *(const float4*)(wp + r * 4);
            }
            // ---- compute 32 k over buf ----
            for (int kq = 0; kq < 8; ++kq) {
                float a[4][4];
                #pragma unroll
                for (int ss = 0; ss < 4; ++ss) {
                    float4 v = *(const float4*)&Alds[buf][sg * 4 + ss][kq * 4];
                    a[ss][0] = v.x; a[ss][1] = v.y; a[ss][2] = v.z; a[ss][3] = v.w;
                }
                #pragma unroll
                for (int c = 0; c < 4; ++c) {
                    float4 w0 = *(const float4*)&Wlds[buf][kq * 4 + c][og * 4];
                    float4 w1 = *(const float4*)&Wlds[buf][kq * 4 + c][64 + og * 4];
                    #pragma unroll
                    for (int ss = 0; ss < 4; ++ss) {
                        acc[ss][0] = fmaf(a[ss][c], w0.x, acc[ss][0]);
                        acc[ss][1] = fmaf(a[ss][c], w0.y, acc[ss][1]);
                        acc[ss][2] = fmaf(a[ss][c], w0.z, acc[ss][2]);
                        acc[ss][3] = fmaf(a[ss][c], w0.w, acc[ss][3]);
                        acc[ss][4] = fmaf(a[ss][c], w1.x, acc[ss][4]);
                        acc[ss][5] = fmaf(a[ss][c], w1.y, acc[ss][5]);
                        acc[ss][6] = fmaf(a[ss][c], w1.z, acc[ss][6]);
                        acc[ss][7] = fmaf(a[ss][c], w1.w, acc[ss][7]);
                    }
                }
            }
            // write next chunk into the OTHER buffer (disjoint from buf -> safe pre-barrier)
            if (kc + 1 < 36) {
                const int nb = buf ^ 1;
                *(float4*)&Alds[nb][sA][kqA * 4]      = aSt[0];
                *(float4*)&Alds[nb][sA][kqA * 4 + 16] = aSt[1];
                #pragma unroll
                for (int r = 0; r < 4; ++r) {
                    Wlds[nb][khW * 16 + r * 4 + 0][oW] = wSt[r].x;
                    Wlds[nb][khW * 16 + r * 4 + 1][oW] = wSt[r].y;
                    Wlds[nb][khW * 16 + r * 4 + 2][oW] = wSt[r].z;
                    Wlds[nb][khW * 16 + r * 4 + 3][oW] = wSt[r].w;
                }
            }
            __syncthreads();
            buf ^= 1;
        }

        // ---- epilogue for this o-chunk: bias, norm^2 partial, 9 prompt-dot partials ----
        const float* sbp = sig_b + i * EE + oc * BN4;
        #pragma unroll
        for (int half = 0; half < 2; ++half) {
            #pragma unroll
            for (int j = 0; j < 4; ++j) {
                const int o_loc = half * 64 + og * 4 + j;
                const float sb = sbp[o_loc];
                #pragma unroll
                for (int ss = 0; ss < 4; ++ss) {
                    float r = acc[ss][half * 4 + j] + sb;
                    norm2[ss] = fmaf(r, r, norm2[ss]);
                    #pragma unroll
                    for (int n = 0; n < NEm; ++n)
                        dots[ss][n] = fmaf(r, Plds[n][oc * BN4 + o_loc], dots[ss][n]);
                }
            }
        }
    }

    // butterfly-reduce across the 16 og lanes (low 4 bits -> DPP-friendly offsets)
    #pragma unroll
    for (int off = 8; off >= 1; off >>= 1) {
        #pragma unroll
        for (int ss = 0; ss < 4; ++ss) {
            norm2[ss] += __shfl_xor(norm2[ss], off, 64);
            #pragma unroll
            for (int n = 0; n < NEm; ++n)
                dots[ss][n] += __shfl_xor(dots[ss][n], off, 64);
        }
    }
    if (og == 0) {
        #pragma unroll
        for (int ss = 0; ss < 4; ++ss) {
            const int s = s0 + sg * 4 + ss;
            if (s < SS) {
                const float scale = 100.0f / sqrtf(norm2[ss]);
                #pragma unroll
                for (int n = 0; n < NEm; ++n)
                    scores[(((size_t)(i * TT + t)) * NEm + n) * SS + s] = dots[ss][n] * scale;
            }
        }
    }
}

// ---------------- K5a: softmax over s, mean over levels ----------------
// grid (9,64), block 256
__global__ __launch_bounds__(256) void k_softmax_mean(
    const float* __restrict__ scores, float* __restrict__ attmean)
{
    const int n = blockIdx.x, t = blockIdx.y, tid = threadIdx.x;
    __shared__ float red[4];
    float accum[3] = {0.f, 0.f, 0.f};
    for (int i = 0; i < 4; ++i) {
        const float* src = scores + (((size_t)(i * TT + t)) * NEm + n) * SS;
        float v[3];
        #pragma unroll
        for (int r = 0; r < 3; ++r) {
            int s = tid + r * 256;
            v[r] = (s < SS) ? src[s] : -3.402823466e+38f;
        }
        float m = blk_reduce(fmaxf(fmaxf(v[0], v[1]), v[2]), true, red);
        float e[3]; float ps = 0.f;
        #pragma unroll
        for (int r = 0; r < 3; ++r) {
            int s = tid + r * 256;
            e[r] = (s < SS) ? expf(v[r] - m) : 0.f;
            ps += e[r];
        }
        float sum = blk_reduce(ps, false, red);
        float invs = 0.25f / sum;
        #pragma unroll
        for (int r = 0; r < 3; ++r) accum[r] = fmaf(e[r], invs, accum[r]);
    }
    #pragma unroll
    for (int r = 0; r < 3; ++r) {
        int s = tid + r * 256;
        if (s < SS) attmean[((size_t)t * NEm + n) * SS + s] = accum[r];
    }
}

// ---------------- K5b: max over emotions ----------------
// grid 64, block 256
__global__ void k_maxatt(const float* __restrict__ attmean, float* __restrict__ maxatt)
{
    const int t = blockIdx.x, tid = threadIdx.x;
    for (int s = tid; s < SS; s += 256) {
        float m = attmean[((size_t)t * NEm) * SS + s];
        for (int n = 1; n < NEm; ++n) m = fmaxf(m, attmean[((size_t)t * NEm + n) * SS + s]);
        maxatt[t * SS + s] = m;
    }
}

// ---------------- K6: attention-scaled 2x2 pooled tokens ----------------
// grid (4,64) = (quadrant, t), block 256
__global__ __launch_bounds__(256) void k_tokens(
    const float* __restrict__ ov, const float* __restrict__ maxatt,
    float* __restrict__ toks, float* __restrict__ sigflat)
{
    const int q = blockIdx.x, t = blockIdx.y, tid = threadIdx.x;
    const int gy0 = (q >> 1) ? 13 : 0, gx0 = (q & 1) ? 13 : 0;
    __shared__ float att[196];
    __shared__ int sidx[196];
    __shared__ float red[4];
    float part = 0.f;
    for (int c = tid; c < 196; c += 256) {
        int gy = gy0 + c / 14, gx = gx0 + c % 14;
        int s = gy * 27 + gx;
        float a = maxatt[t * SS + s];
        att[c] = a; sidx[c] = s; part += a;
    }
    float den = blk_reduce(part, false, red) * (1.0f / 196.0f);
    if (tid == 0) sigflat[t * 4 + q] = den;
    float scale = (1.0f / 196.0f) / (den + 1e-8f);
    for (int h = tid; h < HH; h += 256) {
        float acc = 0.f;
        for (int c = 0; c < 196; ++c)
            acc = fmaf(ov[((size_t)t * SS + sidx[c]) * HH + h], att[c], acc);
        toks[((size_t)t * 4 + q) * HH + h] = acc * scale;
    }
}

// ---------------- K7a: Q projection ----------------
// grid 256 (t*4+q), block 256
__global__ __launch_bounds__(256) void k_q(
    const float* __restrict__ toks, const float* __restrict__ q_w,
    const float* __restrict__ q_b, float* __restrict__ qtmp)
{
    const int tq = blockIdx.x, tid = threadIdx.x;
    __shared__ float tok[HH];
    for (int h = tid; h < HH; h += 256) tok[h] = toks[(size_t)tq * HH + h];
    __syncthreads();
    #pragma unroll
    for (int rep = 0; rep < 2; ++rep) {
        int e = tid + rep * 256;
        const float* wr = q_w + (size_t)e * HH;
        float acc = q_b[e];
        for (int h = 0; h < HH; ++h) acc = fmaf(tok[h], wr[h], acc);
        qtmp[(size_t)tq * EE + e] = acc;
    }
}

// ---------------- K7b: fold k_w into Q  (qk = k_w^T Q, qconst = Q.k_b) ----------------
// grid 256, block 256
__global__ __launch_bounds__(256) void k_qk(
    const float* __restrict__ qtmp, const float* __restrict__ k_w,
    const float* __restrict__ k_b, float* __restrict__ qk, float* __restrict__ qconst)
{
    const int tq = blockIdx.x, tid = threadIdx.x;
    __shared__ float qrow[EE];
    __shared__ float red[4];
    for (int e = tid; e < EE; e += 256) qrow[e] = qtmp[(size_t)tq * EE + e];
    __syncthreads();
    float part = 0.f;
    for (int e = tid; e < EE; e += 256) part = fmaf(qrow[e], k_b[e], part);
    float qc = blk_reduce(part, false, red);
    if (tid == 0) qconst[tq] = qc;
    for (int h = tid; h < HH; h += 256) {
        float acc = 0.f;
        for (int e = 0; e < EE; ++e) acc = fmaf(qrow[e], k_w[(size_t)e * HH + h], acc);
        qk[(size_t)tq * HH + h] = acc;
    }
}

// ---------------- K8: q-former attention (logits + softmax + weighted sum) ----------------
// grid 64 (t), block 256 (4 waves)
__global__ __launch_bounds__(256) void k_attn(
    const float* __restrict__ ov, const float* __restrict__ qk,
    const float* __restrict__ qconst, float* __restrict__ major)
{
    const int t = blockIdx.x, tid = threadIdx.x;
    const int wid = tid >> 6, lane = tid & 63;
    __shared__ float qkl[4][HH];
    __shared__ float aw[4][736];
    __shared__ float qc[4];
    __shared__ float red[4];
    for (int idx = tid; idx < 4 * HH; idx += 256)
        ((float*)qkl)[idx] = qk[(size_t)(t * 4) * HH + idx];
    if (tid < 4) qc[tid] = qconst[t * 4 + tid];
    __syncthreads();
    const float invsq = 0.04419417382415922f;  // 1/sqrt(512)
    for (int s = wid; s < SS; s += 4) {
        const float* row = ov + ((size_t)t * SS + s) * HH;
        float a0 = 0.f, a1 = 0.f, a2 = 0.f, a3 = 0.f;
        for (int h = lane; h < HH; h += 64) {
            float v = row[h];
            a0 = fmaf(v, qkl[0][h], a0);
            a1 = fmaf(v, qkl[1][h], a1);
            a2 = fmaf(v, qkl[2][h], a2);
            a3 = fmaf(v, qkl[3][h], a3);
        }
        #pragma unroll
        for (int off = 32; off >= 1; off >>= 1) {
            a0 += __shfl_xor(a0, off, 64);
            a1 += __shfl_xor(a1, off, 64);
            a2 += __shfl_xor(a2, off, 64);
            a3 += __shfl_xor(a3, off, 64);
        }
        if (lane == 0) {
            aw[0][s] = (a0 + qc[0]) * invsq;
            aw[1][s] = (a1 + qc[1]) * invsq;
            aw[2][s] = (a2 + qc[2]) * invsq;
            aw[3][s] = (a3 + qc[3]) * invsq;
        }
    }
    __syncthreads();
    for (int q = 0; q < 4; ++q) {
        float pm = -3.402823466e+38f;
        for (int s = tid; s < SS; s += 256) pm = fmaxf(pm, aw[q][s]);
        float m = blk_reduce(pm, true, red);
        float ps = 0.f;
        for (int s = tid; s < SS; s += 256) { float e = expf(aw[q][s] - m); aw[q][s] = e; ps += e; }
        float sum = blk_reduce(ps, false, red);
        float inv = 1.0f / sum;
        for (int s = tid; s < SS; s += 256) aw[q][s] *= inv;
    }
    __syncthreads();
    for (int h = tid; h < HH; h += 256) {
        float m0 = 0.f, m1 = 0.f, m2 = 0.f, m3 = 0.f;
        for (int s = 0; s < SS; ++s) {
            float v = ov[((size_t)t * SS + s) * HH + h];
            m0 = fmaf(aw[0][s], v, m0);
            m1 = fmaf(aw[1][s], v, m1);
            m2 = fmaf(aw[2][s], v, m2);
            m3 = fmaf(aw[3][s], v, m3);
        }
        major[((size_t)t * 4 + 0) * HH + h] = m0;
        major[((size_t)t * 4 + 1) * HH + h] = m1;
        major[((size_t)t * 4 + 2) * HH + h] = m2;
        major[((size_t)t * 4 + 3) * HH + h] = m3;
    }
}

// ---------------- K9: significance-weighted per-image mean ----------------
// grid 8, block 256.  patch_emotion_scores == 1/729 exactly (softmax row-mean).
__global__ __launch_bounds__(256) void k_final(
    const float* __restrict__ major, const float* __restrict__ sigflat,
    float* __restrict__ fin)
{
    const int b = blockIdx.x, tid = threadIdx.x;
    __shared__ float g[32];
    __shared__ float dsum;
    if (tid < 32) g[tid] = sigflat[b * 32 + tid] * (1.0f / 729.0f);
    __syncthreads();
    if (tid == 0) {
        float s = 0.f;
        for (int j = 0; j < 32; ++j) s += g[j];
        dsum = 1.0f / (s * (1.0f / 32.0f) + 1e-8f);
    }
    __syncthreads();
    float invd = dsum;
    for (int h = tid; h < HH; h += 256) {
        float acc = 0.f;
        for (int j = 0; j < 32; ++j)
            acc = fmaf(major[((size_t)b * 32 + j) * HH + h], g[j], acc);
        fin[b * HH + h] = acc * (1.0f / 32.0f) * invd;
    }
}

// ---------------- K10: prediction head ----------------
// grid 8, block 512
__global__ __launch_bounds__(512) void k_preds(
    const float* __restrict__ fin, const float* __restrict__ w1, const float* __restrict__ b1,
    const float* __restrict__ w2, const float* __restrict__ b2, float* __restrict__ preds)
{
    const int b = blockIdx.x, tid = threadIdx.x;
    __shared__ float fr[HH];
    __shared__ float h1[EE];
    __shared__ float lg[NEm];
    for (int h = tid; h < HH; h += 512) fr[h] = fin[b * HH + h];
    __syncthreads();
    float acc = b1[tid];
    const float* wr = w1 + (size_t)tid * HH;
    for (int h = 0; h < HH; ++h) acc = fmaf(fr[h], wr[h], acc);
    h1[tid] = 0.5f * acc * (1.0f + erff(acc * GELU_K));
    __syncthreads();
    if (tid < NEm) {
        float a = b2[tid];
        const float* w2r = w2 + (size_t)tid * EE;
        for (int c = 0; c < EE; ++c) a = fmaf(h1[c], w2r[c], a);
        lg[tid] = a;
    }
    __syncthreads();
    if (tid == 0) {
        float m = lg[0];
        for (int n = 1; n < NEm; ++n) m = fmaxf(m, lg[n]);
        float s = 0.f; float e[NEm];
        for (int n = 0; n < NEm; ++n) { e[n] = expf(lg[n] - m); s += e[n]; }
        float inv = 1.0f / s;
        for (int n = 0; n < NEm; ++n) preds[b * NEm + n] = e[n] * inv;
    }
}

// ---------------- launcher ----------------
extern "C" void kernel_launch(void* const* d_in, const int* in_sizes, int n_in,
                              void* d_out, int out_size, void* d_ws, size_t ws_size,
                              hipStream_t stream)
{
    (void)in_sizes; (void)n_in; (void)out_size; (void)ws_size;
    const float* ov       = (const float*)d_in[0];
    const float* sig      = (const float*)d_in[1];
    const float* emo      = (const float*)d_in[2];
    const float* pool_w   = (const float*)d_in[3];
    const float* pool_b   = (const float*)d_in[4];
    const float* cls_w1   = (const float*)d_in[5];
    const float* cls_b1   = (const float*)d_in[6];
    const float* cls_w2   = (const float*)d_in[7];
    const float* cls_b2   = (const float*)d_in[8];
    const float* sig_w    = (const float*)d_in[9];
    const float* sig_b    = (const float*)d_in[10];
    const float* prompt_w = (const float*)d_in[11];
    const float* prompt_b = (const float*)d_in[12];
    const float* pred_w1  = (const float*)d_in[13];
    const float* pred_b1  = (const float*)d_in[14];
    const float* pred_w2  = (const float*)d_in[15];
    const float* pred_b2  = (const float*)d_in[16];
    const float* q_w      = (const float*)d_in[17];
    const float* q_b      = (const float*)d_in[18];
    const float* k_w      = (const float*)d_in[19];
    const float* k_b      = (const float*)d_in[20];

    float* out = (float*)d_out;
    float* ws  = (float*)d_ws;
    float* pooled  = ws;                   // 8*1152      = 9216
    float* cls     = pooled  + 9216;       // 8*512       = 4096
    float* prompts = cls     + 4096;       // 4*8*9*512   = 147456
    float* scores  = prompts + 147456;     // 4*64*9*729  = 1679616
    float* attmean = scores  + 1679616;    // 64*9*729    = 419904
    float* maxatt  = attmean + 419904;     // 64*729      = 46656
    float* toks    = maxatt  + 46656;      // 64*4*1152   = 294912
    float* sigflat = toks    + 294912;     // 64*4        = 256
    float* qtmp    = sigflat + 256;        // 256*512     = 131072
    float* qk      = qtmp    + 131072;     // 256*1152    = 294912
    float* qconst  = qk      + 294912;     // 256

    float* major = out;                    // 64*4*1152 = 294912
    float* fin   = out + 294912;           // 8*1*1152  = 9216
    float* preds = out + 294912 + 9216;    // 8*9       = 72

    hipLaunchKernelGGL(k_pool,         dim3(8, 9),    dim3(128), 0, stream, ov, pool_w, pool_b, pooled);
    hipLaunchKernelGGL(k_cls,          dim3(8),       dim3(512), 0, stream, pooled, cls_w1, cls_b1, cls_w2, cls_b2, cls);
    hipLaunchKernelGGL(k_prompts,      dim3(9, 8, 4), dim3(256), 0, stream, emo, cls, prompt_w, prompt_b, prompts);
    hipLaunchKernelGGL(k_sigscores,    dim3(12, 64, 4), dim3(256), 0, stream, sig, sig_w, sig_b, prompts, scores);
    hipLaunchKernelGGL(k_softmax_mean, dim3(9, 64),   dim3(256), 0, stream, scores, attmean);
    hipLaunchKernelGGL(k_maxatt,       dim3(64),      dim3(256), 0, stream, attmean, maxatt);
    hipLaunchKernelGGL(k_tokens,       dim3(4, 64),   dim3(256), 0, stream, ov, maxatt, toks, sigflat);
    hipLaunchKernelGGL(k_q,            dim3(256),     dim3(256), 0, stream, toks, q_w, q_b, qtmp);
    hipLaunchKernelGGL(k_qk,           dim3(256),     dim3(256), 0, stream, qtmp, k_w, k_b, qk, qconst);
    hipLaunchKernelGGL(k_attn,         dim3(64),      dim3(256), 0, stream, ov, qk, qconst, major);
    hipLaunchKernelGGL(k_final,        dim3(8),       dim3(256), 0, stream, major, sigflat, fin);
    hipLaunchKernelGGL(k_preds,        dim3(8),       dim3(512), 0, stream, fin, pred_w1, pred_b1, pred_w2, pred_b2, preds);
}